// Round 1
// baseline (686.109 us; speedup 1.0000x reference)
//
#include <hip/hip_runtime.h>
#include <hip/hip_bf16.h>

typedef __attribute__((ext_vector_type(8))) short bf16x8;
typedef __attribute__((ext_vector_type(4))) float f32x4;
typedef __attribute__((ext_vector_type(8))) unsigned short u16x8;

__device__ __forceinline__ unsigned short bf16_rne(float f) {
  union { float f; unsigned u; } c; c.f = f;
  unsigned u = c.u;
  return (unsigned short)((u + 0x7FFFu + ((u >> 16) & 1u)) >> 16);
}

// ---------------- prep: pack D (on-the-fly DCT-II basis), w1^T, w2^T into
// MFMA fragment-linear bf16 layout: [kstep][nfrag][lane][j], element =
// Beff[kstep*32 + (lane>>4)*8 + j][nfrag*16 + (lane&15)] ----------------
__global__ void fecam_prep(const float* __restrict__ w1, const float* __restrict__ w2,
                           unsigned short* __restrict__ Dp, unsigned short* __restrict__ w1p,
                           unsigned short* __restrict__ w2p) {
  int t = blockIdx.x * 256 + threadIdx.x;   // one fragment-row (64 lanes each write 8 elems)
  int lane = t & 63;
  int fr = t >> 6;                           // fragment index
  int l16 = lane & 15, lh = lane >> 4;
  unsigned short o[8];
  if (fr < 512) {                            // D: K=512 (16 ksteps), N=512 (NF=32)
    int kstep = fr >> 5, nf = fr & 31;
    int n = nf * 16 + l16;
#pragma unroll
    for (int j = 0; j < 8; ++j) {
      int k = kstep * 32 + lh * 8 + j;
      int tt = (n * (2 * k + 1)) & 2047;     // exact angle reduction mod 2*pi
      float v = 2.0f * cosf((float)tt * 3.0679615757712823e-3f); // pi/1024
      o[j] = bf16_rne(v);
    }
    *(u16x8*)(Dp + (size_t)t * 8) = *(u16x8*)o;
  } else if (fr < 1536) {                    // w1^T: K=512 (16 ksteps), N=1024 (NF=64)
    int fr2 = fr - 512;
    int nf = fr2 & 63;
    int kstep = fr2 >> 6;
    int n = nf * 16 + l16;
#pragma unroll
    for (int j = 0; j < 8; ++j) {
      int k = kstep * 32 + lh * 8 + j;
      o[j] = bf16_rne(w1[(size_t)n * 512 + k]);
    }
    *(u16x8*)(w1p + ((size_t)fr2 * 64 + lane) * 8) = *(u16x8*)o;
  } else {                                   // w2^T: K=1024 (32 ksteps), N=512 (NF=32)
    int fr3 = fr - 1536;
    int nf = fr3 & 31;
    int kstep = fr3 >> 5;
    int n = nf * 16 + l16;
#pragma unroll
    for (int j = 0; j < 8; ++j) {
      int k = kstep * 32 + lh * 8 + j;
      o[j] = bf16_rne(w2[(size_t)n * 1024 + k]);
    }
    *(u16x8*)(w2p + ((size_t)fr3 * 64 + lane) * 8) = *(u16x8*)o;
  }
}

// ---------------- fused main kernel: BM=64 rows (one b, 64 consecutive c),
// 8 waves, each wave owns a 64-col strip. ----------------
__global__ __launch_bounds__(512, 2) void fecam_main(
    const float* __restrict__ x, const float* __restrict__ gamma, const float* __restrict__ beta,
    const unsigned short* __restrict__ Dp, const unsigned short* __restrict__ w1p,
    const unsigned short* __restrict__ w2p, float* __restrict__ out) {
  extern __shared__ char smem[];
  char* bufA = smem;                 // 64KB: x-rows bf16 (later: h half) [64][512] swizzled
  char* bufS = smem + 65536;         // 64KB: sd bf16 [64][512] swizzled
  float* rs1 = (float*)(smem + 131072);  // LN1 row sums [64]
  float* rq1 = rs1 + 64;                 // LN1 row sumsq
  float* rs2 = rq1 + 64;                 // LN2 row sums
  float* rq2 = rs2 + 64;                 // LN2 row sumsq

  const int tid = threadIdx.x;
  const int lane = tid & 63;
  const int w = tid >> 6;
  const int l16 = lane & 15, lh = lane >> 4;
  const int b = blockIdx.x >> 3;
  const int c0 = (blockIdx.x & 7) * 64;
  const int n0 = w * 64;

  if (tid < 256) rs1[tid] = 0.0f;  // zeros all 4 stat arrays (4*64 floats)

  // ---- phase 0: stage x rows -> bufA as bf16, XOR-swizzled row-major ----
  {
    const int cc = tid & 63;      // row (c offset)
    const int ks = tid >> 6;      // 0..7
    const float* xb = x + ((size_t)b * 512) * 512 + c0 + cc;
#pragma unroll 4
    for (int kb = 0; kb < 32; ++kb) {
      int k = kb * 16 + ks * 2;
      float v0 = xb[(size_t)k * 512];
      float v1 = xb[(size_t)(k + 1) * 512];
      unsigned pk = (unsigned)bf16_rne(v0) | ((unsigned)bf16_rne(v1) << 16);
      int byte = (cc * 1024 + k * 2) ^ ((cc & 7) << 4);
      *(unsigned*)(bufA + byte) = pk;
    }
  }

  float g_[4], b_[4];
#pragma unroll
  for (int j = 0; j < 4; ++j) {
    g_[j] = gamma[n0 + j * 16 + l16];
    b_[j] = beta[n0 + j * 16 + l16];
  }

  __syncthreads();

  // ---- GEMM1: freq[64][512] = Xrows @ D^T ----
  f32x4 acc[4][4];
#pragma unroll
  for (int i = 0; i < 4; ++i)
#pragma unroll
    for (int j = 0; j < 4; ++j) acc[i][j] = (f32x4){0.f, 0.f, 0.f, 0.f};

  for (int kstep = 0; kstep < 16; ++kstep) {
    bf16x8 af[4];
#pragma unroll
    for (int i = 0; i < 4; ++i) {
      int r = i * 16 + l16;
      int byte = (r * 1024 + kstep * 64 + lh * 16) ^ ((r & 7) << 4);
      af[i] = *(const bf16x8*)(bufA + byte);
    }
#pragma unroll
    for (int j = 0; j < 4; ++j) {
      bf16x8 bf = *(const bf16x8*)(Dp + (((size_t)kstep * 32 + (w * 4 + j)) * 64 + lane) * 8);
#pragma unroll
      for (int i = 0; i < 4; ++i)
        acc[i][j] = __builtin_amdgcn_mfma_f32_16x16x32_bf16(af[i], bf, acc[i][j], 0, 0, 0);
    }
  }

  // ---- LN1 stats: per-row sum / sumsq over this wave's 64 cols, then LDS atomics ----
#pragma unroll
  for (int i = 0; i < 4; ++i) {
#pragma unroll
    for (int q = 0; q < 4; ++q) {
      float s = acc[i][0][q] + acc[i][1][q] + acc[i][2][q] + acc[i][3][q];
      float ss = acc[i][0][q] * acc[i][0][q] + acc[i][1][q] * acc[i][1][q] +
                 acc[i][2][q] * acc[i][2][q] + acc[i][3][q] * acc[i][3][q];
#pragma unroll
      for (int m = 1; m <= 8; m <<= 1) {
        s += __shfl_xor(s, m);
        ss += __shfl_xor(ss, m);
      }
      if (l16 == 0) {
        atomicAdd(&rs1[i * 16 + lh * 4 + q], s);
        atomicAdd(&rq1[i * 16 + lh * 4 + q], ss);
      }
    }
  }
  __syncthreads();

  // ---- normalize -> sd (bf16) into bufS ----
#pragma unroll
  for (int i = 0; i < 4; ++i) {
#pragma unroll
    for (int q = 0; q < 4; ++q) {
      int r = i * 16 + lh * 4 + q;
      float mu = rs1[r] * (1.0f / 512.0f);
      float var = rq1[r] * (1.0f / 512.0f) - mu * mu;
      float rstd = rsqrtf(var + 1e-6f);
#pragma unroll
      for (int j = 0; j < 4; ++j) {
        int col = n0 + j * 16 + l16;
        float v = (acc[i][j][q] - mu) * rstd * g_[j] + b_[j];
        int byte = (r * 1024 + col * 2) ^ ((r & 7) << 4);
        *(unsigned short*)(bufS + byte) = bf16_rne(v);
      }
    }
  }
  __syncthreads();

  // ---- two N-halves of h: GEMM2 (sd @ w1^T, relu) -> bufA, GEMM3 (h @ w2^T) accumulate ----
  f32x4 acc3[4][4];
#pragma unroll
  for (int i = 0; i < 4; ++i)
#pragma unroll
    for (int j = 0; j < 4; ++j) acc3[i][j] = (f32x4){0.f, 0.f, 0.f, 0.f};

  for (int half = 0; half < 2; ++half) {
    f32x4 acc2[4][4];
#pragma unroll
    for (int i = 0; i < 4; ++i)
#pragma unroll
      for (int j = 0; j < 4; ++j) acc2[i][j] = (f32x4){0.f, 0.f, 0.f, 0.f};

    for (int kstep = 0; kstep < 16; ++kstep) {
      bf16x8 af[4];
#pragma unroll
      for (int i = 0; i < 4; ++i) {
        int r = i * 16 + l16;
        int byte = (r * 1024 + kstep * 64 + lh * 16) ^ ((r & 7) << 4);
        af[i] = *(const bf16x8*)(bufS + byte);
      }
#pragma unroll
      for (int j = 0; j < 4; ++j) {
        bf16x8 bf = *(const bf16x8*)(
            w1p + (((size_t)kstep * 64 + (half * 32 + w * 4 + j)) * 64 + lane) * 8);
#pragma unroll
        for (int i = 0; i < 4; ++i)
          acc2[i][j] = __builtin_amdgcn_mfma_f32_16x16x32_bf16(af[i], bf, acc2[i][j], 0, 0, 0);
      }
    }

    __syncthreads();  // bufA's previous readers (GEMM1 / GEMM3 half-0) are done

    // relu -> h (bf16) into bufA
#pragma unroll
    for (int i = 0; i < 4; ++i) {
#pragma unroll
      for (int q = 0; q < 4; ++q) {
        int r = i * 16 + lh * 4 + q;
#pragma unroll
        for (int j = 0; j < 4; ++j) {
          int col = n0 + j * 16 + l16;  // local col within this half
          float v = fmaxf(acc2[i][j][q], 0.0f);
          int byte = (r * 1024 + col * 2) ^ ((r & 7) << 4);
          *(unsigned short*)(bufA + byte) = bf16_rne(v);
        }
      }
    }
    __syncthreads();

    // GEMM3: accumulate this half's K contribution
    for (int kstep = 0; kstep < 16; ++kstep) {
      bf16x8 af[4];
#pragma unroll
      for (int i = 0; i < 4; ++i) {
        int r = i * 16 + l16;
        int byte = (r * 1024 + kstep * 64 + lh * 16) ^ ((r & 7) << 4);
        af[i] = *(const bf16x8*)(bufA + byte);
      }
#pragma unroll
      for (int j = 0; j < 4; ++j) {
        bf16x8 bf = *(const bf16x8*)(
            w2p + (((size_t)(half * 16 + kstep) * 32 + (w * 4 + j)) * 64 + lane) * 8);
#pragma unroll
        for (int i = 0; i < 4; ++i)
          acc3[i][j] = __builtin_amdgcn_mfma_f32_16x16x32_bf16(af[i], bf, acc3[i][j], 0, 0, 0);
      }
    }
  }

  // ---- sigmoid ----
#pragma unroll
  for (int i = 0; i < 4; ++i)
#pragma unroll
    for (int j = 0; j < 4; ++j)
#pragma unroll
      for (int q = 0; q < 4; ++q)
        acc3[i][j][q] = 1.0f / (1.0f + __expf(-acc3[i][j][q]));

  // ---- LN2 stats ----
#pragma unroll
  for (int i = 0; i < 4; ++i) {
#pragma unroll
    for (int q = 0; q < 4; ++q) {
      float s = acc3[i][0][q] + acc3[i][1][q] + acc3[i][2][q] + acc3[i][3][q];
      float ss = acc3[i][0][q] * acc3[i][0][q] + acc3[i][1][q] * acc3[i][1][q] +
                 acc3[i][2][q] * acc3[i][2][q] + acc3[i][3][q] * acc3[i][3][q];
#pragma unroll
      for (int m = 1; m <= 8; m <<= 1) {
        s += __shfl_xor(s, m);
        ss += __shfl_xor(ss, m);
      }
      if (l16 == 0) {
        atomicAdd(&rs2[i * 16 + lh * 4 + q], s);
        atomicAdd(&rq2[i * 16 + lh * 4 + q], ss);
      }
    }
  }
  __syncthreads();

  // ---- LN2 normalize, multiply by xp, store (out[b][col][c0+r]) ----
#pragma unroll
  for (int i = 0; i < 4; ++i) {
#pragma unroll
    for (int j = 0; j < 4; ++j) {
      int col = n0 + j * 16 + l16;
      size_t base = ((size_t)b * 512 + col) * 512 + c0 + i * 16 + lh * 4;
      float4 xv = *(const float4*)(x + base);
      float4 ov;
#pragma unroll
      for (int q = 0; q < 4; ++q) {
        int r = i * 16 + lh * 4 + q;
        float mu = rs2[r] * (1.0f / 512.0f);
        float var = rq2[r] * (1.0f / 512.0f) - mu * mu;
        float rstd = rsqrtf(var + 1e-6f);
        float fn = (acc3[i][j][q] - mu) * rstd * g_[j] + b_[j];
        (&ov.x)[q] = (&xv.x)[q] * fn;
      }
      *(float4*)(out + base) = ov;
    }
  }
}

extern "C" void kernel_launch(void* const* d_in, const int* in_sizes, int n_in,
                              void* d_out, int out_size, void* d_ws, size_t ws_size,
                              hipStream_t stream) {
  const float* x = (const float*)d_in[0];
  const float* gamma = (const float*)d_in[1];
  const float* beta = (const float*)d_in[2];
  const float* w1 = (const float*)d_in[3];
  const float* w2 = (const float*)d_in[4];

  unsigned short* Dp = (unsigned short*)d_ws;        // 16*32*64*8  = 262144 bf16
  unsigned short* w1p = Dp + 262144;                 // 16*64*64*8  = 524288 bf16
  unsigned short* w2p = w1p + 524288;                // 32*32*64*8  = 524288 bf16

  fecam_prep<<<640, 256, 0, stream>>>(w1, w2, Dp, w1p, w2p);
  fecam_main<<<1024, 512, 132096, stream>>>(x, gamma, beta, Dp, w1p, w2p, (float*)d_out);
}

// Round 2
// 555.008 us; speedup vs baseline: 1.2362x; 1.2362x over previous
//
#include <hip/hip_runtime.h>
#include <hip/hip_bf16.h>

typedef __attribute__((ext_vector_type(8))) short bf16x8;
typedef __attribute__((ext_vector_type(4))) float f32x4;
typedef __attribute__((ext_vector_type(8))) unsigned short u16x8;

__device__ __forceinline__ unsigned short bf16_rne(float f) {
  union { float f; unsigned u; } c; c.f = f;
  unsigned u = c.u;
  return (unsigned short)((u + 0x7FFFu + ((u >> 16) & 1u)) >> 16);
}

// ---------------- prep: pack D (on-the-fly DCT-II basis), w1^T, w2^T into
// MFMA fragment-linear bf16 layout: [kstep][nfrag][lane][j], element =
// Beff[kstep*32 + (lane>>4)*8 + j][nfrag*16 + (lane&15)] ----------------
__global__ void fecam_prep(const float* __restrict__ w1, const float* __restrict__ w2,
                           unsigned short* __restrict__ Dp, unsigned short* __restrict__ w1p,
                           unsigned short* __restrict__ w2p) {
  int t = blockIdx.x * 256 + threadIdx.x;   // one fragment-row (64 lanes each write 8 elems)
  int lane = t & 63;
  int fr = t >> 6;                           // fragment index
  int l16 = lane & 15, lh = lane >> 4;
  unsigned short o[8];
  if (fr < 512) {                            // D: K=512 (16 ksteps), N=512 (NF=32)
    int kstep = fr >> 5, nf = fr & 31;
    int n = nf * 16 + l16;
#pragma unroll
    for (int j = 0; j < 8; ++j) {
      int k = kstep * 32 + lh * 8 + j;
      int tt = (n * (2 * k + 1)) & 2047;     // exact angle reduction mod 2*pi
      float v = 2.0f * cosf((float)tt * 3.0679615757712823e-3f); // pi/1024
      o[j] = bf16_rne(v);
    }
    *(u16x8*)(Dp + (size_t)t * 8) = *(u16x8*)o;
  } else if (fr < 1536) {                    // w1^T: K=512 (16 ksteps), N=1024 (NF=64)
    int fr2 = fr - 512;
    int nf = fr2 & 63;
    int kstep = fr2 >> 6;
    int n = nf * 16 + l16;
#pragma unroll
    for (int j = 0; j < 8; ++j) {
      int k = kstep * 32 + lh * 8 + j;
      o[j] = bf16_rne(w1[(size_t)n * 512 + k]);
    }
    *(u16x8*)(w1p + ((size_t)fr2 * 64 + lane) * 8) = *(u16x8*)o;
  } else {                                   // w2^T: K=1024 (32 ksteps), N=512 (NF=32)
    int fr3 = fr - 1536;
    int nf = fr3 & 31;
    int kstep = fr3 >> 5;
    int n = nf * 16 + l16;
#pragma unroll
    for (int j = 0; j < 8; ++j) {
      int k = kstep * 32 + lh * 8 + j;
      o[j] = bf16_rne(w2[(size_t)n * 1024 + k]);
    }
    *(u16x8*)(w2p + ((size_t)fr3 * 64 + lane) * 8) = *(u16x8*)o;
  }
}

// ---------------- fused main kernel: BM=32 rows (one b, 32 consecutive c),
// 8 waves, each wave owns a 64-col strip. LDS = 66KB -> 2 blocks/CU. ----------------
__global__ __launch_bounds__(512, 4) void fecam_main(
    const float* __restrict__ x, const float* __restrict__ gamma, const float* __restrict__ beta,
    const unsigned short* __restrict__ Dp, const unsigned short* __restrict__ w1p,
    const unsigned short* __restrict__ w2p, float* __restrict__ out) {
  extern __shared__ char smem[];
  char* bufX = smem;                 // 32KB: x-rows bf16 (later: h halves) [32][512] swizzled
  char* bufS = smem + 32768;         // 32KB: sd bf16 [32][512] swizzled
  float* rs1 = (float*)(smem + 65536);   // LN1 row sums [32]
  float* rq1 = rs1 + 32;                 // LN1 row sumsq
  float* rs2 = rq1 + 32;                 // LN2 row sums
  float* rq2 = rs2 + 32;                 // LN2 row sumsq

  const int tid = threadIdx.x;
  const int lane = tid & 63;
  const int w = tid >> 6;
  const int l16 = lane & 15, lh = lane >> 4;
  const int b = blockIdx.x >> 4;
  const int c0 = (blockIdx.x & 15) * 32;
  const int n0 = w * 64;

  if (tid < 128) rs1[tid] = 0.0f;  // zeros all 4 stat arrays (4*32 floats)

  // ---- phase 0: stage x rows -> bufX as bf16, XOR-swizzled row-major ----
  {
    const int cc = tid & 31;      // row (c offset)
    const int kg = tid >> 5;      // 0..15
    const float* xb = x + ((size_t)b * 512) * 512 + c0 + cc;
#pragma unroll 4
    for (int kb = 0; kb < 16; ++kb) {
      int k = kb * 32 + kg * 2;
      float v0 = xb[(size_t)k * 512];
      float v1 = xb[(size_t)(k + 1) * 512];
      unsigned pk = (unsigned)bf16_rne(v0) | ((unsigned)bf16_rne(v1) << 16);
      int byte = (cc * 1024 + k * 2) ^ ((cc & 7) << 4);
      *(unsigned*)(bufX + byte) = pk;
    }
  }

  float g_[4], b_[4];
#pragma unroll
  for (int j = 0; j < 4; ++j) {
    g_[j] = gamma[n0 + j * 16 + l16];
    b_[j] = beta[n0 + j * 16 + l16];
  }

  __syncthreads();

  // ---- GEMM1: freq[32][512] = Xrows @ D^T ----
  f32x4 acc[2][4];
#pragma unroll
  for (int i = 0; i < 2; ++i)
#pragma unroll
    for (int j = 0; j < 4; ++j) acc[i][j] = (f32x4){0.f, 0.f, 0.f, 0.f};

  for (int kstep = 0; kstep < 16; ++kstep) {
    bf16x8 af[2];
#pragma unroll
    for (int i = 0; i < 2; ++i) {
      int r = i * 16 + l16;
      int byte = (r * 1024 + kstep * 64 + lh * 16) ^ ((r & 7) << 4);
      af[i] = *(const bf16x8*)(bufX + byte);
    }
#pragma unroll
    for (int j = 0; j < 4; ++j) {
      bf16x8 bf = *(const bf16x8*)(Dp + (((size_t)kstep * 32 + (w * 4 + j)) * 64 + lane) * 8);
#pragma unroll
      for (int i = 0; i < 2; ++i)
        acc[i][j] = __builtin_amdgcn_mfma_f32_16x16x32_bf16(af[i], bf, acc[i][j], 0, 0, 0);
    }
  }

  // ---- LN1 stats: per-row sum / sumsq over this wave's 64 cols, then LDS atomics ----
#pragma unroll
  for (int i = 0; i < 2; ++i) {
#pragma unroll
    for (int q = 0; q < 4; ++q) {
      float s = acc[i][0][q] + acc[i][1][q] + acc[i][2][q] + acc[i][3][q];
      float ss = acc[i][0][q] * acc[i][0][q] + acc[i][1][q] * acc[i][1][q] +
                 acc[i][2][q] * acc[i][2][q] + acc[i][3][q] * acc[i][3][q];
#pragma unroll
      for (int m = 1; m <= 8; m <<= 1) {
        s += __shfl_xor(s, m);
        ss += __shfl_xor(ss, m);
      }
      if (l16 == 0) {
        atomicAdd(&rs1[i * 16 + lh * 4 + q], s);
        atomicAdd(&rq1[i * 16 + lh * 4 + q], ss);
      }
    }
  }
  __syncthreads();

  // ---- normalize -> sd (bf16) into bufS ----
#pragma unroll
  for (int i = 0; i < 2; ++i) {
#pragma unroll
    for (int q = 0; q < 4; ++q) {
      int r = i * 16 + lh * 4 + q;
      float mu = rs1[r] * (1.0f / 512.0f);
      float var = rq1[r] * (1.0f / 512.0f) - mu * mu;
      float rstd = rsqrtf(var + 1e-6f);
#pragma unroll
      for (int j = 0; j < 4; ++j) {
        int col = n0 + j * 16 + l16;
        float v = (acc[i][j][q] - mu) * rstd * g_[j] + b_[j];
        int byte = (r * 1024 + col * 2) ^ ((r & 7) << 4);
        *(unsigned short*)(bufS + byte) = bf16_rne(v);
      }
    }
  }
  __syncthreads();

  // ---- two N-halves of h: GEMM2 (sd @ w1^T, relu) -> bufX, GEMM3 (h @ w2^T) accumulate ----
  f32x4 acc3[2][4];
#pragma unroll
  for (int i = 0; i < 2; ++i)
#pragma unroll
    for (int j = 0; j < 4; ++j) acc3[i][j] = (f32x4){0.f, 0.f, 0.f, 0.f};

  for (int half = 0; half < 2; ++half) {
    f32x4 acc2[2][4];
#pragma unroll
    for (int i = 0; i < 2; ++i)
#pragma unroll
      for (int j = 0; j < 4; ++j) acc2[i][j] = (f32x4){0.f, 0.f, 0.f, 0.f};

    for (int kstep = 0; kstep < 16; ++kstep) {
      bf16x8 af[2];
#pragma unroll
      for (int i = 0; i < 2; ++i) {
        int r = i * 16 + l16;
        int byte = (r * 1024 + kstep * 64 + lh * 16) ^ ((r & 7) << 4);
        af[i] = *(const bf16x8*)(bufS + byte);
      }
#pragma unroll
      for (int j = 0; j < 4; ++j) {
        bf16x8 bf = *(const bf16x8*)(
            w1p + (((size_t)kstep * 64 + (half * 32 + w * 4 + j)) * 64 + lane) * 8);
#pragma unroll
        for (int i = 0; i < 2; ++i)
          acc2[i][j] = __builtin_amdgcn_mfma_f32_16x16x32_bf16(af[i], bf, acc2[i][j], 0, 0, 0);
      }
    }

    __syncthreads();  // bufX's previous readers (GEMM1 / GEMM3 half-0) are done

    // relu -> h (bf16) into bufX
#pragma unroll
    for (int i = 0; i < 2; ++i) {
#pragma unroll
      for (int q = 0; q < 4; ++q) {
        int r = i * 16 + lh * 4 + q;
#pragma unroll
        for (int j = 0; j < 4; ++j) {
          int col = n0 + j * 16 + l16;  // local col within this half
          float v = fmaxf(acc2[i][j][q], 0.0f);
          int byte = (r * 1024 + col * 2) ^ ((r & 7) << 4);
          *(unsigned short*)(bufX + byte) = bf16_rne(v);
        }
      }
    }
    __syncthreads();

    // GEMM3: accumulate this half's K contribution
    for (int kstep = 0; kstep < 16; ++kstep) {
      bf16x8 af[2];
#pragma unroll
      for (int i = 0; i < 2; ++i) {
        int r = i * 16 + l16;
        int byte = (r * 1024 + kstep * 64 + lh * 16) ^ ((r & 7) << 4);
        af[i] = *(const bf16x8*)(bufX + byte);
      }
#pragma unroll
      for (int j = 0; j < 4; ++j) {
        bf16x8 bf = *(const bf16x8*)(
            w2p + (((size_t)(half * 16 + kstep) * 32 + (w * 4 + j)) * 64 + lane) * 8);
#pragma unroll
        for (int i = 0; i < 2; ++i)
          acc3[i][j] = __builtin_amdgcn_mfma_f32_16x16x32_bf16(af[i], bf, acc3[i][j], 0, 0, 0);
      }
    }
  }

  // ---- sigmoid ----
#pragma unroll
  for (int i = 0; i < 2; ++i)
#pragma unroll
    for (int j = 0; j < 4; ++j)
#pragma unroll
      for (int q = 0; q < 4; ++q)
        acc3[i][j][q] = 1.0f / (1.0f + __expf(-acc3[i][j][q]));

  // ---- LN2 stats ----
#pragma unroll
  for (int i = 0; i < 2; ++i) {
#pragma unroll
    for (int q = 0; q < 4; ++q) {
      float s = acc3[i][0][q] + acc3[i][1][q] + acc3[i][2][q] + acc3[i][3][q];
      float ss = acc3[i][0][q] * acc3[i][0][q] + acc3[i][1][q] * acc3[i][1][q] +
                 acc3[i][2][q] * acc3[i][2][q] + acc3[i][3][q] * acc3[i][3][q];
#pragma unroll
      for (int m = 1; m <= 8; m <<= 1) {
        s += __shfl_xor(s, m);
        ss += __shfl_xor(ss, m);
      }
      if (l16 == 0) {
        atomicAdd(&rs2[i * 16 + lh * 4 + q], s);
        atomicAdd(&rq2[i * 16 + lh * 4 + q], ss);
      }
    }
  }
  __syncthreads();

  // ---- LN2 normalize, multiply by xp, store (out[b][col][c0+r]) ----
#pragma unroll
  for (int i = 0; i < 2; ++i) {
#pragma unroll
    for (int j = 0; j < 4; ++j) {
      int col = n0 + j * 16 + l16;
      size_t base = ((size_t)b * 512 + col) * 512 + c0 + i * 16 + lh * 4;
      float4 xv = *(const float4*)(x + base);
      float4 ov;
#pragma unroll
      for (int q = 0; q < 4; ++q) {
        int r = i * 16 + lh * 4 + q;
        float mu = rs2[r] * (1.0f / 512.0f);
        float var = rq2[r] * (1.0f / 512.0f) - mu * mu;
        float rstd = rsqrtf(var + 1e-6f);
        float fn = (acc3[i][j][q] - mu) * rstd * g_[j] + b_[j];
        (&ov.x)[q] = (&xv.x)[q] * fn;
      }
      *(float4*)(out + base) = ov;
    }
  }
}

extern "C" void kernel_launch(void* const* d_in, const int* in_sizes, int n_in,
                              void* d_out, int out_size, void* d_ws, size_t ws_size,
                              hipStream_t stream) {
  const float* x = (const float*)d_in[0];
  const float* gamma = (const float*)d_in[1];
  const float* beta = (const float*)d_in[2];
  const float* w1 = (const float*)d_in[3];
  const float* w2 = (const float*)d_in[4];

  unsigned short* Dp = (unsigned short*)d_ws;        // 16*32*64*8  = 262144 bf16
  unsigned short* w1p = Dp + 262144;                 // 16*64*64*8  = 524288 bf16
  unsigned short* w2p = w1p + 524288;                // 32*32*64*8  = 524288 bf16

  fecam_prep<<<640, 256, 0, stream>>>(w1, w2, Dp, w1p, w2p);
  fecam_main<<<2048, 512, 66048, stream>>>(x, gamma, beta, Dp, w1p, w2p, (float*)d_out);
}

// Round 3
// 337.827 us; speedup vs baseline: 2.0309x; 1.6429x over previous
//
#include <hip/hip_runtime.h>
#include <hip/hip_bf16.h>

typedef __attribute__((ext_vector_type(8))) short bf16x8;
typedef __attribute__((ext_vector_type(4))) float f32x4;
typedef __attribute__((ext_vector_type(8))) unsigned short u16x8;

__device__ __forceinline__ unsigned short bf16_rne(float f) {
  union { float f; unsigned u; } c; c.f = f;
  unsigned u = c.u;
  return (unsigned short)((u + 0x7FFFu + ((u >> 16) & 1u)) >> 16);
}

// ---------------- prep: pack D (on-the-fly DCT-II basis), w1^T, w2^T into
// MFMA fragment-linear bf16 layout: [kstep][nfrag][lane][j], element =
// Beff[kstep*32 + (lane>>4)*8 + j][nfrag*16 + (lane&15)] ----------------
__global__ void fecam_prep(const float* __restrict__ w1, const float* __restrict__ w2,
                           unsigned short* __restrict__ Dp, unsigned short* __restrict__ w1p,
                           unsigned short* __restrict__ w2p) {
  int t = blockIdx.x * 256 + threadIdx.x;
  int lane = t & 63;
  int fr = t >> 6;
  int l16 = lane & 15, lh = lane >> 4;
  unsigned short o[8];
  if (fr < 512) {                            // D: K=512 (16 ksteps), N=512 (NF=32)
    int kstep = fr >> 5, nf = fr & 31;
    int n = nf * 16 + l16;
#pragma unroll
    for (int j = 0; j < 8; ++j) {
      int k = kstep * 32 + lh * 8 + j;
      int tt = (n * (2 * k + 1)) & 2047;     // exact angle reduction mod 2*pi
      float v = 2.0f * cosf((float)tt * 3.0679615757712823e-3f); // pi/1024
      o[j] = bf16_rne(v);
    }
    *(u16x8*)(Dp + (size_t)t * 8) = *(u16x8*)o;
  } else if (fr < 1536) {                    // w1^T: K=512 (16 ksteps), N=1024 (NF=64)
    int fr2 = fr - 512;
    int nf = fr2 & 63;
    int kstep = fr2 >> 6;
    int n = nf * 16 + l16;
#pragma unroll
    for (int j = 0; j < 8; ++j) {
      int k = kstep * 32 + lh * 8 + j;
      o[j] = bf16_rne(w1[(size_t)n * 512 + k]);
    }
    *(u16x8*)(w1p + ((size_t)fr2 * 64 + lane) * 8) = *(u16x8*)o;
  } else {                                   // w2^T: K=1024 (32 ksteps), N=512 (NF=32)
    int fr3 = fr - 1536;
    int nf = fr3 & 31;
    int kstep = fr3 >> 5;
    int n = nf * 16 + l16;
#pragma unroll
    for (int j = 0; j < 8; ++j) {
      int k = kstep * 32 + lh * 8 + j;
      o[j] = bf16_rne(w2[(size_t)n * 1024 + k]);
    }
    *(u16x8*)(w2p + ((size_t)fr3 * 64 + lane) * 8) = *(u16x8*)o;
  }
}

// ---------------- fused main: BM=64 rows (one b, 64 consecutive c), 1024 thr
// = 16 waves, 1M x 16N wave split (each B-fragment read ONCE per block).
// LDS 99KB -> 1 block/CU, 16 waves. ----------------
__global__ __launch_bounds__(1024, 4) void fecam_main(
    const float* __restrict__ x, const float* __restrict__ gamma, const float* __restrict__ beta,
    const unsigned short* __restrict__ Dp, const unsigned short* __restrict__ w1p,
    const unsigned short* __restrict__ w2p, float* __restrict__ out) {
  extern __shared__ char smem[];
  char* bufS = smem;                 // 64KB: x bf16 [64][512] swz, then sd (in place)
  char* bufH = smem + 65536;         // 32KB: h quarter [64][256] bf16 swz
  float* rs1 = (float*)(smem + 98304);   // LN1 row sums [64]
  float* rq1 = rs1 + 64;
  float* rs2 = rq1 + 64;
  float* rq2 = rs2 + 64;

  const int tid = threadIdx.x;
  const int lane = tid & 63;
  const int w = tid >> 6;            // wave 0..15
  const int l16 = lane & 15, lh = lane >> 4;
  const int b = blockIdx.x >> 3;
  const int c0 = (blockIdx.x & 7) * 64;
  const int n0 = w * 32;             // this wave's 32-col strip (GEMM1/3/epilogue)

  if (tid < 256) rs1[tid] = 0.0f;    // zero all 4 stat arrays (4*64 floats)

  // ---- phase 0: stage x rows -> bufS as bf16, XOR-swizzled [64][512] ----
  {
    const int cc = tid & 63;         // row (c offset); full wave = 64 consecutive c
    const int kg = tid >> 6;         // 0..15 (k-pair group)
    const float* xb = x + ((size_t)b * 512) * 512 + c0 + cc;
#pragma unroll
    for (int kb = 0; kb < 16; ++kb) {
      int k = kb * 32 + kg * 2;
      float v0 = xb[(size_t)k * 512];
      float v1 = xb[(size_t)(k + 1) * 512];
      unsigned pk = (unsigned)bf16_rne(v0) | ((unsigned)bf16_rne(v1) << 16);
      int byte = (cc * 1024 + k * 2) ^ ((cc & 7) << 4);
      *(unsigned*)(bufS + byte) = pk;
    }
  }

  float g_[2], b_[2];
#pragma unroll
  for (int jj = 0; jj < 2; ++jj) {
    g_[jj] = gamma[n0 + jj * 16 + l16];
    b_[jj] = beta[n0 + jj * 16 + l16];
  }

  __syncthreads();

  // ---- GEMM1: freq[64][512] = Xrows @ D^T ; wave computes 64 rows x 32 cols ----
  f32x4 acc1[4][2];
#pragma unroll
  for (int i = 0; i < 4; ++i)
#pragma unroll
    for (int jj = 0; jj < 2; ++jj) acc1[i][jj] = (f32x4){0.f, 0.f, 0.f, 0.f};

#pragma unroll 2
  for (int kstep = 0; kstep < 16; ++kstep) {
    bf16x8 af[4];
#pragma unroll
    for (int i = 0; i < 4; ++i) {
      int r = i * 16 + l16;
      int byte = (r * 1024 + kstep * 64 + lh * 16) ^ ((r & 7) << 4);
      af[i] = *(const bf16x8*)(bufS + byte);
    }
#pragma unroll
    for (int jj = 0; jj < 2; ++jj) {
      bf16x8 bf = *(const bf16x8*)(Dp + (((size_t)kstep * 32 + (w * 2 + jj)) * 64 + lane) * 8);
#pragma unroll
      for (int i = 0; i < 4; ++i)
        acc1[i][jj] = __builtin_amdgcn_mfma_f32_16x16x32_bf16(af[i], bf, acc1[i][jj], 0, 0, 0);
    }
  }

  // ---- LN1 stats over this wave's 32 cols -> LDS atomics ----
#pragma unroll
  for (int i = 0; i < 4; ++i) {
#pragma unroll
    for (int q = 0; q < 4; ++q) {
      float s = acc1[i][0][q] + acc1[i][1][q];
      float ss = acc1[i][0][q] * acc1[i][0][q] + acc1[i][1][q] * acc1[i][1][q];
#pragma unroll
      for (int m = 1; m <= 8; m <<= 1) {
        s += __shfl_xor(s, m);
        ss += __shfl_xor(ss, m);
      }
      if (l16 == 0) {
        atomicAdd(&rs1[i * 16 + lh * 4 + q], s);
        atomicAdd(&rq1[i * 16 + lh * 4 + q], ss);
      }
    }
  }
  __syncthreads();   // all GEMM1 x-reads done; stats complete

  // ---- normalize -> sd (bf16) into bufS (overwrites x, now dead) ----
#pragma unroll
  for (int i = 0; i < 4; ++i) {
#pragma unroll
    for (int q = 0; q < 4; ++q) {
      int r = i * 16 + lh * 4 + q;
      float mu = rs1[r] * (1.0f / 512.0f);
      float var = rq1[r] * (1.0f / 512.0f) - mu * mu;
      float rstd = rsqrtf(var + 1e-6f);
#pragma unroll
      for (int jj = 0; jj < 2; ++jj) {
        int col = n0 + jj * 16 + l16;
        float v = (acc1[i][jj][q] - mu) * rstd * g_[jj] + b_[jj];
        int byte = (r * 1024 + col * 2) ^ ((r & 7) << 4);
        *(unsigned short*)(bufS + byte) = bf16_rne(v);
      }
    }
  }
  __syncthreads();

  // ---- 4 quarters of h: GEMM2 (sd @ w1^T, relu) -> bufH, GEMM3 (h @ w2^T) acc ----
  f32x4 acc3[4][2];
#pragma unroll
  for (int i = 0; i < 4; ++i)
#pragma unroll
    for (int jj = 0; jj < 2; ++jj) acc3[i][jj] = (f32x4){0.f, 0.f, 0.f, 0.f};

  for (int qh = 0; qh < 4; ++qh) {
    // GEMM2 quarter: wave computes 64 rows x 16 cols (nf = qh*16 + w)
    f32x4 acc2[4];
#pragma unroll
    for (int i = 0; i < 4; ++i) acc2[i] = (f32x4){0.f, 0.f, 0.f, 0.f};

#pragma unroll 2
    for (int kstep = 0; kstep < 16; ++kstep) {
      bf16x8 af[4];
#pragma unroll
      for (int i = 0; i < 4; ++i) {
        int r = i * 16 + l16;
        int byte = (r * 1024 + kstep * 64 + lh * 16) ^ ((r & 7) << 4);
        af[i] = *(const bf16x8*)(bufS + byte);
      }
      bf16x8 bf = *(const bf16x8*)(
          w1p + (((size_t)kstep * 64 + (qh * 16 + w)) * 64 + lane) * 8);
#pragma unroll
      for (int i = 0; i < 4; ++i)
        acc2[i] = __builtin_amdgcn_mfma_f32_16x16x32_bf16(af[i], bf, acc2[i], 0, 0, 0);
    }

    __syncthreads();   // previous quarter's GEMM3 readers of bufH are done

    // relu -> h quarter (bf16) into bufH [64][256] swz
#pragma unroll
    for (int i = 0; i < 4; ++i) {
#pragma unroll
      for (int q = 0; q < 4; ++q) {
        int r = i * 16 + lh * 4 + q;
        int loc = w * 16 + l16;
        float v = fmaxf(acc2[i][q], 0.0f);
        int byte = (r * 512 + loc * 2) ^ ((r & 7) << 4);
        *(unsigned short*)(bufH + byte) = bf16_rne(v);
      }
    }
    __syncthreads();

    // GEMM3 quarter: K=256 (8 ksteps), wave computes 64 rows x 32 cols
#pragma unroll 2
    for (int kstep = 0; kstep < 8; ++kstep) {
      bf16x8 af[4];
#pragma unroll
      for (int i = 0; i < 4; ++i) {
        int r = i * 16 + l16;
        int byte = (r * 512 + kstep * 64 + lh * 16) ^ ((r & 7) << 4);
        af[i] = *(const bf16x8*)(bufH + byte);
      }
#pragma unroll
      for (int jj = 0; jj < 2; ++jj) {
        bf16x8 bf = *(const bf16x8*)(
            w2p + (((size_t)(qh * 8 + kstep) * 32 + (w * 2 + jj)) * 64 + lane) * 8);
#pragma unroll
        for (int i = 0; i < 4; ++i)
          acc3[i][jj] = __builtin_amdgcn_mfma_f32_16x16x32_bf16(af[i], bf, acc3[i][jj], 0, 0, 0);
      }
    }
  }

  // ---- sigmoid ----
#pragma unroll
  for (int i = 0; i < 4; ++i)
#pragma unroll
    for (int jj = 0; jj < 2; ++jj)
#pragma unroll
      for (int q = 0; q < 4; ++q)
        acc3[i][jj][q] = 1.0f / (1.0f + __expf(-acc3[i][jj][q]));

  // ---- LN2 stats ----
#pragma unroll
  for (int i = 0; i < 4; ++i) {
#pragma unroll
    for (int q = 0; q < 4; ++q) {
      float s = acc3[i][0][q] + acc3[i][1][q];
      float ss = acc3[i][0][q] * acc3[i][0][q] + acc3[i][1][q] * acc3[i][1][q];
#pragma unroll
      for (int m = 1; m <= 8; m <<= 1) {
        s += __shfl_xor(s, m);
        ss += __shfl_xor(ss, m);
      }
      if (l16 == 0) {
        atomicAdd(&rs2[i * 16 + lh * 4 + q], s);
        atomicAdd(&rq2[i * 16 + lh * 4 + q], ss);
      }
    }
  }
  __syncthreads();

  // ---- LN2 normalize, multiply by xp, store out[b][col][c0+r] ----
#pragma unroll
  for (int i = 0; i < 4; ++i) {
#pragma unroll
    for (int jj = 0; jj < 2; ++jj) {
      int col = n0 + jj * 16 + l16;
      size_t base = ((size_t)b * 512 + col) * 512 + c0 + i * 16 + lh * 4;
      float4 xv = *(const float4*)(x + base);
      float4 ov;
#pragma unroll
      for (int q = 0; q < 4; ++q) {
        int r = i * 16 + lh * 4 + q;
        float mu = rs2[r] * (1.0f / 512.0f);
        float var = rq2[r] * (1.0f / 512.0f) - mu * mu;
        float rstd = rsqrtf(var + 1e-6f);
        float fn = (acc3[i][jj][q] - mu) * rstd * g_[jj] + b_[jj];
        (&ov.x)[q] = (&xv.x)[q] * fn;
      }
      *(float4*)(out + base) = ov;
    }
  }
}

extern "C" void kernel_launch(void* const* d_in, const int* in_sizes, int n_in,
                              void* d_out, int out_size, void* d_ws, size_t ws_size,
                              hipStream_t stream) {
  const float* x = (const float*)d_in[0];
  const float* gamma = (const float*)d_in[1];
  const float* beta = (const float*)d_in[2];
  const float* w1 = (const float*)d_in[3];
  const float* w2 = (const float*)d_in[4];

  unsigned short* Dp = (unsigned short*)d_ws;        // 16*32*64*8  = 262144 bf16
  unsigned short* w1p = Dp + 262144;                 // 16*64*64*8  = 524288 bf16
  unsigned short* w2p = w1p + 524288;                // 32*32*64*8  = 524288 bf16

  fecam_prep<<<640, 256, 0, stream>>>(w1, w2, Dp, w1p, w2p);
  fecam_main<<<1024, 1024, 99328, stream>>>(x, gamma, beta, Dp, w1p, w2p, (float*)d_out);
}